// Round 9
// baseline (272.585 us; speedup 1.0000x reference)
//
#include <hip/hip_runtime.h>
#include <hip/hip_bf16.h>

#define N_NODES 50000
#define N_EDGES 800000
#define FIN 256
#define EMB 128
#define NGRAPH 256
#define TOT_E (N_EDGES + N_NODES)
#define NCHUNK 32          // edge chunks per range in scatter3
#define NRANGE 49          // ceil(N_NODES/1024)

typedef __bf16 bf16;
typedef __attribute__((ext_vector_type(8))) __bf16 bf16x8;
typedef __attribute__((ext_vector_type(2))) __bf16 bf16x2;
typedef __attribute__((ext_vector_type(4))) float f32x4;
typedef __attribute__((ext_vector_type(4))) int i32x4;

// ---------------- transpose + cast: W[rows][cols] f32 -> WT[cols][rows] bf16 ----------------
__global__ void transpose_kernel(const float* __restrict__ src, bf16* __restrict__ dst,
                                 int rows, int cols) {
    int t = blockIdx.x * 256 + threadIdx.x;
    if (t >= rows * cols) return;
    int c = t / rows, r = t - c * rows;
    dst[t] = (bf16)src[r * cols + c];
}

// ---------------- CSR build ----------------
// Round-9: scatter reads go non-temporal (MUBUF nt) so the streamed e_dst/e_src
// traffic stops evicting partially-gathered CSR write lines from the XCD L2
// (round-8: WRITE_SIZE bounced back 3.6->32MB from LRU pressure; round-6 proved
// 3.6MB is achievable when write lines stay resident).
__global__ void hist_kernel(const int* __restrict__ e_dst, int* __restrict__ counts) {
    int e = blockIdx.x * 256 + threadIdx.x;
    if (e >= TOT_E) return;
    int d = (e < N_EDGES) ? __builtin_nontemporal_load(e_dst + e) : (e - N_EDGES);
    atomicAdd(&counts[d], 1);
}

__global__ __launch_bounds__(1024)
void scan_block_kernel(const int* __restrict__ counts, int* __restrict__ offsets,
                       int* __restrict__ blocksums) {
    __shared__ int lds[1024];
    int t = threadIdx.x;
    int idx = blockIdx.x * 1024 + t;
    int v = (idx < N_NODES) ? counts[idx] : 0;
    lds[t] = v;
    __syncthreads();
    for (int d = 1; d < 1024; d <<= 1) {
        int u = (t >= d) ? lds[t - d] : 0;
        __syncthreads();
        lds[t] += u;
        __syncthreads();
    }
    if (idx < N_NODES) offsets[idx] = lds[t] - v;     // exclusive within chunk
    if (t == 1023) blocksums[blockIdx.x] = lds[1023];
}

// Adds chunk prefix; seeds cursor[] and the self-loop CSR entry.
__global__ __launch_bounds__(1024)
void scan_fix_kernel(int* __restrict__ offsets, const int* __restrict__ blocksums,
                     int nblk, int* __restrict__ cursor, int* __restrict__ sorted_src) {
    __shared__ int sprefix;
    int t = threadIdx.x, b = blockIdx.x;
    if (t < 64) {
        int v = (t < b && t < nblk) ? blocksums[t] : 0;
#pragma unroll
        for (int mk = 32; mk >= 1; mk >>= 1) v += __shfl_xor(v, mk);
        if (t == 0) sprefix = v;
    }
    __syncthreads();
    int idx = b * 1024 + t;
    if (idx < N_NODES) {
        int off = offsets[idx] + sprefix;
        offsets[idx] = off;
        cursor[idx] = off + 1;       // slot 0 taken by the self-loop
        sorted_src[off] = idx;       // self-loop entry
    }
    if (idx == 0) offsets[N_NODES] = TOT_E;
}

// Block (xcd=bid&7, slot=bid>>3): chunk-major slot order; range r = ri*8+xcd.
__global__ __launch_bounds__(1024)
void scatter_kernel3(const int* __restrict__ e_src, const int* __restrict__ e_dst,
                     int* __restrict__ cursor, int* __restrict__ sorted_src) {
    int bid = blockIdx.x;
    int x = bid & 7;
    int slot = bid >> 3;
    int chunk = slot / 7;
    int ri = slot - chunk * 7;
    int r = ri * 8 + x;
    if (r >= NRANGE) return;
    int lo = r * 1024, hi = lo + 1024;
    const int NQ = N_EDGES / 4;                      // 200000
    int q0 = (int)(((long long)chunk * NQ) / NCHUNK);
    int q1 = (int)(((long long)(chunk + 1) * NQ) / NCHUNK);
    const i32x4* dst4 = (const i32x4*)e_dst;
    const i32x4* src4 = (const i32x4*)e_src;
    for (int i = q0 + threadIdx.x; i < q1; i += 1024) {
        i32x4 d4 = __builtin_nontemporal_load(dst4 + i);   // nt: don't evict CSR lines
        bool i0 = (d4[0] >= lo && d4[0] < hi), i1 = (d4[1] >= lo && d4[1] < hi);
        bool i2 = (d4[2] >= lo && d4[2] < hi), i3 = (d4[3] >= lo && d4[3] < hi);
        if (i0 | i1 | i2 | i3) {
            i32x4 s4 = __builtin_nontemporal_load(src4 + i);
            if (i0) sorted_src[atomicAdd(&cursor[d4[0]], 1)] = s4[0];
            if (i1) sorted_src[atomicAdd(&cursor[d4[1]], 1)] = s4[1];
            if (i2) sorted_src[atomicAdd(&cursor[d4[2]], 1)] = s4[2];
            if (i3) sorted_src[atomicAdd(&cursor[d4[3]], 1)] = s4[3];
        }
    }
}

// ---------------- GEMM + fused attention scores ----------------
// C[M][128] = A[M][K] * W[K][128] (WT[128][K] bf16). Epilogue: each block holds
// full 128-wide h-rows in acc (16 lanes x 8 cols x 4 rows) -> compute
// s_src[row]=h.a_src, s_dst[row]=h.a_dst via 16-lane shfl_xor reduce (saves the
// separate scores kernel: 2 launches + 2 full h re-reads).
template<int K, typename AT>
__global__ __launch_bounds__(256)
void gemm_kernel(const AT* __restrict__ A, const bf16* __restrict__ WT,
                 bf16* __restrict__ C, int M,
                 const float* __restrict__ a_src, const float* __restrict__ a_dst,
                 float* __restrict__ s_src, float* __restrict__ s_dst) {
    __shared__ __align__(16) bf16 As[64][32];
    __shared__ __align__(16) bf16 Bs[128][32];
    int tid = threadIdx.x;
    int wave = tid >> 6, lane = tid & 63;
    int m0 = blockIdx.x * 64;

    f32x4 acc[8];
#pragma unroll
    for (int i = 0; i < 8; ++i) acc[i] = (f32x4){0.f, 0.f, 0.f, 0.f};

    int arow = tid >> 2, aseg = tid & 3;

    for (int k0 = 0; k0 < K; k0 += 32) {
        {
            int gr = m0 + arow;
            if constexpr (sizeof(AT) == 4) {
                bf16x8 av = (bf16x8){0, 0, 0, 0, 0, 0, 0, 0};
                if (gr < M) {
                    const float* ap = (const float*)A + (size_t)gr * K + k0 + aseg * 8;
                    float4 f0 = *(const float4*)(ap);
                    float4 f1 = *(const float4*)(ap + 4);
                    av = (bf16x8){(bf16)f0.x, (bf16)f0.y, (bf16)f0.z, (bf16)f0.w,
                                  (bf16)f1.x, (bf16)f1.y, (bf16)f1.z, (bf16)f1.w};
                }
                *(bf16x8*)(&As[arow][aseg * 8]) = av;
            } else {
                uint4 av = make_uint4(0u, 0u, 0u, 0u);
                if (gr < M) av = *(const uint4*)((const bf16*)A + (size_t)gr * K + k0 + aseg * 8);
                *(uint4*)(&As[arow][aseg * 8]) = av;
            }
        }
#pragma unroll
        for (int it = 0; it < 2; ++it) {
            int c = tid + it * 256;
            int col = c >> 2, seg = c & 3;
            *(uint4*)(&Bs[col][seg * 8]) =
                *(const uint4*)(WT + (size_t)col * K + k0 + seg * 8);
        }
        __syncthreads();
        bf16x8 af = *(const bf16x8*)(&As[wave * 16 + (lane & 15)][(lane >> 4) * 8]);
#pragma unroll
        for (int n = 0; n < 8; ++n) {
            bf16x8 bfr = *(const bf16x8*)(&Bs[n * 16 + (lane & 15)][(lane >> 4) * 8]);
            acc[n] = __builtin_amdgcn_mfma_f32_16x16x32_bf16(af, bfr, acc[n], 0, 0, 0);
        }
        __syncthreads();
    }
    int rbase = m0 + wave * 16 + ((lane >> 4) << 2);
    int cbase = lane & 15;
#pragma unroll
    for (int n = 0; n < 8; ++n) {
#pragma unroll
        for (int r = 0; r < 4; ++r) {
            int row = rbase + r;
            if (row < M) C[(size_t)row * 128 + n * 16 + cbase] = (bf16)acc[n][r];
        }
    }
    // fused scores epilogue
    float a_s[8], a_d[8];
#pragma unroll
    for (int n = 0; n < 8; ++n) {
        a_s[n] = a_src[n * 16 + cbase];
        a_d[n] = a_dst[n * 16 + cbase];
    }
#pragma unroll
    for (int r = 0; r < 4; ++r) {
        float ps = 0.f, pd = 0.f;
#pragma unroll
        for (int n = 0; n < 8; ++n) {
            ps += acc[n][r] * a_s[n];
            pd += acc[n][r] * a_d[n];
        }
#pragma unroll
        for (int mk = 8; mk >= 1; mk >>= 1) {   // reduce across the 16-lane row group
            ps += __shfl_xor(ps, mk);
            pd += __shfl_xor(pd, mk);
        }
        int row = rbase + r;
        if (cbase == 0 && row < M) { s_src[row] = ps; s_dst[row] = pd; }
    }
}

// ---------------- per-node softmax-aggregate (16-lane groups, 4 nodes/wave) ----------------
template<typename OUT_T>
__global__ __launch_bounds__(256)
void agg_kernel(const int* __restrict__ offsets, const int* __restrict__ sorted_src,
                const float* __restrict__ s_src, const float* __restrict__ s_dst,
                const bf16* __restrict__ h, const float* __restrict__ bias,
                OUT_T* __restrict__ out) {
    int tid = threadIdx.x;
    int wave = tid >> 6, lane = tid & 63;
    int gl = lane & 15;
    int gbase = lane & 48;
    int d = blockIdx.x * 16 + wave * 4 + (lane >> 4);
    if (d >= N_NODES) return;
    int r0 = offsets[d];
    int deg = offsets[d + 1] - r0;
    float sd = s_dst[d];

    int sv0 = 0, sv1 = 0;
    float ev0 = -INFINITY, ev1 = -INFINITY;
    if (gl < deg) {
        sv0 = sorted_src[r0 + gl];
        float e = s_src[sv0] + sd;
        ev0 = (e > 0.f) ? e : 0.2f * e;
    }
    if (16 + gl < deg) {
        sv1 = sorted_src[r0 + 16 + gl];
        float e = s_src[sv1] + sd;
        ev1 = (e > 0.f) ? e : 0.2f * e;
    }
    float m = fmaxf(ev0, ev1);
    for (int i = 32 + gl; i < deg; i += 16) {
        int s = sorted_src[r0 + i];
        float e = s_src[s] + sd;
        e = (e > 0.f) ? e : 0.2f * e;
        m = fmaxf(m, e);
    }
#pragma unroll
    for (int mk = 8; mk >= 1; mk >>= 1) m = fmaxf(m, __shfl_xor(m, mk));

    float pv0 = (gl < deg) ? __expf(ev0 - m) : 0.f;
    float pv1 = (16 + gl < deg) ? __expf(ev1 - m) : 0.f;
    float den = pv0 + pv1;
    for (int i = 32 + gl; i < deg; i += 16) {
        int s = sorted_src[r0 + i];
        float e = s_src[s] + sd;
        e = (e > 0.f) ? e : 0.2f * e;
        den += __expf(e - m);
    }
#pragma unroll
    for (int mk = 8; mk >= 1; mk >>= 1) den += __shfl_xor(den, mk);

    float acc[8];
#pragma unroll
    for (int k = 0; k < 8; ++k) acc[k] = 0.f;

    int jm = (deg < 32) ? deg : 32;
#pragma unroll 4
    for (int j = 0; j < jm; ++j) {
        int src_lane = gbase + (j & 15);
        int s = __shfl((j < 16) ? sv0 : sv1, src_lane);
        float p = __shfl((j < 16) ? pv0 : pv1, src_lane);
        bf16x8 hv = *(const bf16x8*)(h + (size_t)s * 128 + gl * 8);
#pragma unroll
        for (int k = 0; k < 8; ++k) acc[k] += p * (float)hv[k];
    }
    for (int i = 32; i < deg; ++i) {
        int s = sorted_src[r0 + i];
        float e = s_src[s] + sd;
        e = (e > 0.f) ? e : 0.2f * e;
        float p = __expf(e - m);
        bf16x8 hv = *(const bf16x8*)(h + (size_t)s * 128 + gl * 8);
#pragma unroll
        for (int k = 0; k < 8; ++k) acc[k] += p * (float)hv[k];
    }

    float inv = 1.f / den;
    float4 bv0 = *(const float4*)(bias + gl * 8);
    float4 bv1 = *(const float4*)(bias + gl * 8 + 4);
    float o[8] = {acc[0] * inv + bv0.x, acc[1] * inv + bv0.y,
                  acc[2] * inv + bv0.z, acc[3] * inv + bv0.w,
                  acc[4] * inv + bv1.x, acc[5] * inv + bv1.y,
                  acc[6] * inv + bv1.z, acc[7] * inv + bv1.w};
    if constexpr (sizeof(OUT_T) == 2) {
        bf16x8 ov;
#pragma unroll
        for (int k = 0; k < 8; ++k) ov[k] = (bf16)o[k];
        *(bf16x8*)((bf16*)out + (size_t)d * 128 + gl * 8) = ov;
    } else {
        float* op = (float*)out + (size_t)d * 128 + gl * 8;
        *(float4*)op       = (float4){o[0], o[1], o[2], o[3]};
        *(float4*)(op + 4) = (float4){o[4], o[5], o[6], o[7]};
    }
}

// ---------------- per-graph mean/max pooling (batch_idx sorted) ----------------
__global__ __launch_bounds__(256)
void pool_kernel(const float* __restrict__ out2, const int* __restrict__ batch_idx,
                 float* __restrict__ mean, float* __restrict__ mx) {
    int g = blockIdx.x;
    int j = threadIdx.x & 127;
    int grp = threadIdx.x >> 7;
    int lo = 0, hi = N_NODES;
    while (lo < hi) { int mid = (lo + hi) >> 1; if (batch_idx[mid] < g) lo = mid + 1; else hi = mid; }
    int start = lo;
    hi = N_NODES;
    while (lo < hi) { int mid = (lo + hi) >> 1; if (batch_idx[mid] < g + 1) lo = mid + 1; else hi = mid; }
    int end = lo;

    float s = 0.f, mmax = -INFINITY;
    for (int r = start + grp; r < end; r += 2) {
        float v = out2[(size_t)r * 128 + j];
        s += v;
        mmax = fmaxf(mmax, v);
    }
    __shared__ float ls[2][128], lm[2][128];
    ls[grp][j] = s; lm[grp][j] = mmax;
    __syncthreads();
    if (grp == 0) {
        int cnt = end - start;
        float sum = ls[0][j] + ls[1][j];
        float mv = fmaxf(lm[0][j], lm[1][j]);
        mean[g * 128 + j] = sum / fmaxf((float)cnt, 1.f);
        mx[g * 128 + j] = (cnt > 0) ? mv : 0.f;
    }
}

// ---------------- head ----------------
__global__ __launch_bounds__(128)
void head_kernel(const float* __restrict__ mean, const float* __restrict__ mx,
                 const float* __restrict__ gfeat, const float* __restrict__ Wg,
                 const float* __restrict__ bg, const float* __restrict__ Wo,
                 const float* __restrict__ bo, float* __restrict__ out) {
    int g = blockIdx.x;
    int j = threadIdx.x;
    float gft = bg[j];
#pragma unroll
    for (int k = 0; k < 32; ++k)
        gft += gfeat[g * 32 + k] * Wg[k * 128 + j];
    float mj = mean[g * 128 + j], xj = mx[g * 128 + j];
    float p0 = mj * Wo[j * 2 + 0] + xj * Wo[(128 + j) * 2 + 0] + gft * Wo[(256 + j) * 2 + 0];
    float p1 = mj * Wo[j * 2 + 1] + xj * Wo[(128 + j) * 2 + 1] + gft * Wo[(256 + j) * 2 + 1];
#pragma unroll
    for (int m = 32; m >= 1; m >>= 1) { p0 += __shfl_xor(p0, m); p1 += __shfl_xor(p1, m); }
    __shared__ float l0s[2], l1s[2];
    int wv = j >> 6;
    if ((j & 63) == 0) { l0s[wv] = p0; l1s[wv] = p1; }
    __syncthreads();
    if (j == 0) {
        float l0 = l0s[0] + l0s[1] + bo[0];
        float l1 = l1s[0] + l1s[1] + bo[1];
        float mm = fmaxf(l0, l1);
        float lse = mm + logf(__expf(l0 - mm) + __expf(l1 - mm));
        out[g * 2 + 0] = l0 - lse;
        out[g * 2 + 1] = l1 - lse;
    }
}

extern "C" void kernel_launch(void* const* d_in, const int* in_sizes, int n_in,
                              void* d_out, int out_size, void* d_ws, size_t ws_size,
                              hipStream_t stream) {
    const float* x     = (const float*)d_in[0];
    const int*   edges = (const int*)d_in[1];
    const int*   batch = (const int*)d_in[2];
    const float* gfeat = (const float*)d_in[3];
    const float* W1    = (const float*)d_in[4];
    const float* a1s   = (const float*)d_in[5];
    const float* a1d   = (const float*)d_in[6];
    const float* b1    = (const float*)d_in[7];
    const float* W2    = (const float*)d_in[8];
    const float* a2s   = (const float*)d_in[9];
    const float* a2d   = (const float*)d_in[10];
    const float* b2    = (const float*)d_in[11];
    const float* Wg    = (const float*)d_in[12];
    const float* bg    = (const float*)d_in[13];
    const float* Wo    = (const float*)d_in[14];
    const float* bo    = (const float*)d_in[15];

    char* ws = (char*)d_ws;
    bf16*  WT1       = (bf16*)(ws + 0);          //  65536 B
    bf16*  WT2       = (bf16*)(ws + 65536);      //  32768 B
    float* s_src     = (float*)(ws + 98304);     // 200704 B
    float* s_dst     = (float*)(ws + 299008);    // 200704 B
    int*   counts    = (int*)(ws + 499712);      // 200000 B
    int*   blocksums = (int*)(ws + 699712);      // 196 B
    int*   offsets   = (int*)(ws + 700416);      // 200704 B (N+1 ints)
    int*   cursor    = (int*)(ws + 901120);      // 200704 B
    int*   sorted    = (int*)(ws + 1101824);     // 3400704 B
    bf16*  h         = (bf16*)(ws + 4502528);    // 12.8 MB
    bf16*  out1      = (bf16*)(ws + 17302528);   // 12.8 MB
    float* out2      = (float*)(ws + 30102528);  // 25.6 MB
    float* pmean     = (float*)(ws + 55702528);  // 131072 B
    float* pmax      = (float*)(ws + 55833600);  // 131072 B

    const int* e_src = edges;
    const int* e_dst = edges + N_EDGES;

    // --- W transposes + f32->bf16 cast (tiny) ---
    transpose_kernel<<<(FIN * EMB + 255) / 256, 256, 0, stream>>>(W1, WT1, FIN, EMB);
    transpose_kernel<<<(EMB * EMB + 255) / 256, 256, 0, stream>>>(W2, WT2, EMB, EMB);

    // --- CSR by dst ---
    hipMemsetAsync(counts, 0, N_NODES * sizeof(int), stream);
    int eb = (TOT_E + 255) / 256;
    hist_kernel<<<eb, 256, 0, stream>>>(e_dst, counts);
    int nblk = (N_NODES + 1023) / 1024;   // 49
    scan_block_kernel<<<nblk, 1024, 0, stream>>>(counts, offsets, blocksums);
    scan_fix_kernel<<<nblk, 1024, 0, stream>>>(offsets, blocksums, nblk, cursor, sorted);
    scatter_kernel3<<<8 * NCHUNK * 7, 1024, 0, stream>>>(e_src, e_dst, cursor, sorted);

    int gemm_blocks = (N_NODES + 63) / 64;
    int agg_blocks = (N_NODES + 15) / 16;

    // --- layer 1 (scores fused into gemm epilogue) ---
    gemm_kernel<FIN, float><<<gemm_blocks, 256, 0, stream>>>(x, WT1, h, N_NODES,
                                                             a1s, a1d, s_src, s_dst);
    agg_kernel<bf16><<<agg_blocks, 256, 0, stream>>>(offsets, sorted, s_src, s_dst, h, b1, out1);

    // --- layer 2 ---
    gemm_kernel<EMB, bf16><<<gemm_blocks, 256, 0, stream>>>(out1, WT2, h, N_NODES,
                                                            a2s, a2d, s_src, s_dst);
    agg_kernel<float><<<agg_blocks, 256, 0, stream>>>(offsets, sorted, s_src, s_dst, h, b2, out2);

    // --- pooling + head ---
    pool_kernel<<<NGRAPH, 256, 0, stream>>>(out2, batch, pmean, pmax);
    head_kernel<<<NGRAPH, 128, 0, stream>>>(pmean, pmax, gfeat, Wg, bg, Wo, bo, (float*)d_out);
}

// Round 10
// 249.626 us; speedup vs baseline: 1.0920x; 1.0920x over previous
//
#include <hip/hip_runtime.h>
#include <hip/hip_bf16.h>

#define N_NODES 50000
#define N_EDGES 800000
#define FIN 256
#define EMB 128
#define NGRAPH 256
#define TOT_E (N_EDGES + N_NODES)
#define NB 391             // buckets of 128 dst-nodes: 391*128 = 50048 >= N
#define NSLOT (NB * 8)     // per-(bucket, blockIdx&7) sub-buckets
#define CAP 448            // entries per sub-bucket; lambda=257, +12 sigma

typedef __bf16 bf16;
typedef __attribute__((ext_vector_type(8))) __bf16 bf16x8;
typedef __attribute__((ext_vector_type(2))) __bf16 bf16x2;
typedef __attribute__((ext_vector_type(4))) float f32x4;
typedef __attribute__((ext_vector_type(4))) int i32x4;

// ---------------- transpose + cast: W[rows][cols] f32 -> WT[cols][rows] bf16 ----------------
__global__ void transpose_kernel(const float* __restrict__ src, bf16* __restrict__ dst,
                                 int rows, int cols) {
    int t = blockIdx.x * 256 + threadIdx.x;
    if (t >= rows * cols) return;
    int c = t / rows, r = t - c * rows;
    dst[t] = (bf16)src[r * cols + c];
}

// ---------------- CSR build, round-10: two-phase bucket sort ----------------
// Round 5/8/9 post-mortems: any structure where a node's CSR line is written by
// temporally-scattered blocks pays ~9-17x HBM write amplification (64B line per
// 4B entry). Phase A appends (dst,src) pairs contiguously into per-(bucket,xcd)
// sub-buckets (append = full line use); Phase B gives each bucket's contiguous
// CSR region to ONE block (LDS hist+scan, self-loops fused) -> write amp ~1.

__global__ __launch_bounds__(256)
void bucket_scatter_kernel(const int* __restrict__ e_src, const int* __restrict__ e_dst,
                           int* __restrict__ subcur, int2* __restrict__ pairs) {
    int i = blockIdx.x * 256 + threadIdx.x;
    const int NQ = N_EDGES / 4;                  // 200000
    if (i >= NQ) return;
    int xs = blockIdx.x & 7;                     // XCD round-robin heuristic
    i32x4 d4 = *(const i32x4*)(e_dst + 4 * i);
    i32x4 s4 = *(const i32x4*)(e_src + 4 * i);
#pragma unroll
    for (int k = 0; k < 4; ++k) {
        int d = d4[k];
        int slot = (d >> 7) * 8 + xs;
        int pos = atomicAdd(&subcur[slot], 1);
        pairs[(size_t)slot * CAP + pos] = make_int2(d, s4[k]);
    }
}

// 1 block: sub-counts -> bucket totals (+valid self-loops) -> exclusive scan.
__global__ __launch_bounds__(1024)
void bucket_scan_kernel(const int* __restrict__ subcur, int* __restrict__ bucketbase,
                        int* __restrict__ offsets) {
    __shared__ int lds[1024];
    int t = threadIdx.x;
    int tot = 0;
    if (t < NB) {
#pragma unroll
        for (int x = 0; x < 8; ++x) tot += subcur[t * 8 + x];
        int lo = t * 128;
        int valid = N_NODES - lo;
        valid = valid < 0 ? 0 : (valid > 128 ? 128 : valid);
        tot += valid;
    }
    lds[t] = tot;
    __syncthreads();
    for (int d = 1; d < 1024; d <<= 1) {
        int u = (t >= d) ? lds[t - d] : 0;
        __syncthreads();
        lds[t] += u;
        __syncthreads();
    }
    if (t < NB) bucketbase[t] = lds[t] - tot;    // exclusive
    if (t == 0) offsets[N_NODES] = TOT_E;
}

// One block per bucket: LDS hist (self-loop seeded) -> LDS scan -> offsets +
// sorted (self at slot 0, pairs after). All writes land in this block's
// contiguous region.
__global__ __launch_bounds__(1024)
void bucket_build_kernel(const int* __restrict__ subcur, const int* __restrict__ bucketbase,
                         const int2* __restrict__ pairs, int* __restrict__ offsets,
                         int* __restrict__ sorted) {
    int b = blockIdx.x;
    int t = threadIdx.x;
    int lo = b * 128;
    int valid = N_NODES - lo;
    valid = valid < 0 ? 0 : (valid > 128 ? 128 : valid);
    __shared__ int cnt[128], sc[128], subc[8];
    __shared__ int bb;
    if (t < 128) cnt[t] = (t < valid) ? 1 : 0;   // self-loop
    if (t < 8) subc[t] = subcur[b * 8 + t];
    if (t == 0) bb = bucketbase[b];
    __syncthreads();
    // pass 1: histogram
    for (int x = 0; x < 8; ++x) {
        int c = subc[x];
        const int2* P = pairs + (size_t)(b * 8 + x) * CAP;
        for (int i = t; i < c; i += 1024)
            atomicAdd(&cnt[P[i].x & 127], 1);
    }
    __syncthreads();
    int v = (t < 128) ? cnt[t] : 0;
    if (t < 128) sc[t] = v;
    __syncthreads();
    for (int dd = 1; dd < 128; dd <<= 1) {       // Hillis-Steele inclusive
        int u = (t < 128 && t >= dd) ? sc[t - dd] : 0;
        __syncthreads();
        if (t < 128) sc[t] += u;
        __syncthreads();
    }
    if (t < valid) {
        int off = bb + (sc[t] - v);              // exclusive
        offsets[lo + t] = off;
        sorted[off] = lo + t;                    // self-loop entry
    }
    __syncthreads();
    if (t < 128) cnt[t] = (sc[t] - v) + ((t < valid) ? 1 : 0);  // cursor (rel.)
    __syncthreads();
    // pass 2: place pairs
    for (int x = 0; x < 8; ++x) {
        int c = subc[x];
        const int2* P = pairs + (size_t)(b * 8 + x) * CAP;
        for (int i = t; i < c; i += 1024) {
            int2 pr = P[i];
            int pos = atomicAdd(&cnt[pr.x & 127], 1);
            sorted[bb + pos] = pr.y;
        }
    }
}

// ---------------- GEMM + fused attention scores ----------------
template<int K, typename AT>
__global__ __launch_bounds__(256)
void gemm_kernel(const AT* __restrict__ A, const bf16* __restrict__ WT,
                 bf16* __restrict__ C, int M,
                 const float* __restrict__ a_src, const float* __restrict__ a_dst,
                 float* __restrict__ s_src, float* __restrict__ s_dst) {
    __shared__ __align__(16) bf16 As[64][32];
    __shared__ __align__(16) bf16 Bs[128][32];
    int tid = threadIdx.x;
    int wave = tid >> 6, lane = tid & 63;
    int m0 = blockIdx.x * 64;

    f32x4 acc[8];
#pragma unroll
    for (int i = 0; i < 8; ++i) acc[i] = (f32x4){0.f, 0.f, 0.f, 0.f};

    int arow = tid >> 2, aseg = tid & 3;

    for (int k0 = 0; k0 < K; k0 += 32) {
        {
            int gr = m0 + arow;
            if constexpr (sizeof(AT) == 4) {
                bf16x8 av = (bf16x8){0, 0, 0, 0, 0, 0, 0, 0};
                if (gr < M) {
                    const float* ap = (const float*)A + (size_t)gr * K + k0 + aseg * 8;
                    float4 f0 = *(const float4*)(ap);
                    float4 f1 = *(const float4*)(ap + 4);
                    av = (bf16x8){(bf16)f0.x, (bf16)f0.y, (bf16)f0.z, (bf16)f0.w,
                                  (bf16)f1.x, (bf16)f1.y, (bf16)f1.z, (bf16)f1.w};
                }
                *(bf16x8*)(&As[arow][aseg * 8]) = av;
            } else {
                uint4 av = make_uint4(0u, 0u, 0u, 0u);
                if (gr < M) av = *(const uint4*)((const bf16*)A + (size_t)gr * K + k0 + aseg * 8);
                *(uint4*)(&As[arow][aseg * 8]) = av;
            }
        }
#pragma unroll
        for (int it = 0; it < 2; ++it) {
            int c = tid + it * 256;
            int col = c >> 2, seg = c & 3;
            *(uint4*)(&Bs[col][seg * 8]) =
                *(const uint4*)(WT + (size_t)col * K + k0 + seg * 8);
        }
        __syncthreads();
        bf16x8 af = *(const bf16x8*)(&As[wave * 16 + (lane & 15)][(lane >> 4) * 8]);
#pragma unroll
        for (int n = 0; n < 8; ++n) {
            bf16x8 bfr = *(const bf16x8*)(&Bs[n * 16 + (lane & 15)][(lane >> 4) * 8]);
            acc[n] = __builtin_amdgcn_mfma_f32_16x16x32_bf16(af, bfr, acc[n], 0, 0, 0);
        }
        __syncthreads();
    }
    int rbase = m0 + wave * 16 + ((lane >> 4) << 2);
    int cbase = lane & 15;
#pragma unroll
    for (int n = 0; n < 8; ++n) {
#pragma unroll
        for (int r = 0; r < 4; ++r) {
            int row = rbase + r;
            if (row < M) C[(size_t)row * 128 + n * 16 + cbase] = (bf16)acc[n][r];
        }
    }
    // fused scores epilogue
    float a_s[8], a_d[8];
#pragma unroll
    for (int n = 0; n < 8; ++n) {
        a_s[n] = a_src[n * 16 + cbase];
        a_d[n] = a_dst[n * 16 + cbase];
    }
#pragma unroll
    for (int r = 0; r < 4; ++r) {
        float ps = 0.f, pd = 0.f;
#pragma unroll
        for (int n = 0; n < 8; ++n) {
            ps += acc[n][r] * a_s[n];
            pd += acc[n][r] * a_d[n];
        }
#pragma unroll
        for (int mk = 8; mk >= 1; mk >>= 1) {
            ps += __shfl_xor(ps, mk);
            pd += __shfl_xor(pd, mk);
        }
        int row = rbase + r;
        if (cbase == 0 && row < M) { s_src[row] = ps; s_dst[row] = pd; }
    }
}

// ---------------- per-node softmax-aggregate (16-lane groups, 4 nodes/wave) ----------------
template<typename OUT_T>
__global__ __launch_bounds__(256)
void agg_kernel(const int* __restrict__ offsets, const int* __restrict__ sorted_src,
                const float* __restrict__ s_src, const float* __restrict__ s_dst,
                const bf16* __restrict__ h, const float* __restrict__ bias,
                OUT_T* __restrict__ out) {
    int tid = threadIdx.x;
    int wave = tid >> 6, lane = tid & 63;
    int gl = lane & 15;
    int gbase = lane & 48;
    int d = blockIdx.x * 16 + wave * 4 + (lane >> 4);
    if (d >= N_NODES) return;
    int r0 = offsets[d];
    int deg = offsets[d + 1] - r0;
    float sd = s_dst[d];

    int sv0 = 0, sv1 = 0;
    float ev0 = -INFINITY, ev1 = -INFINITY;
    if (gl < deg) {
        sv0 = sorted_src[r0 + gl];
        float e = s_src[sv0] + sd;
        ev0 = (e > 0.f) ? e : 0.2f * e;
    }
    if (16 + gl < deg) {
        sv1 = sorted_src[r0 + 16 + gl];
        float e = s_src[sv1] + sd;
        ev1 = (e > 0.f) ? e : 0.2f * e;
    }
    float m = fmaxf(ev0, ev1);
    for (int i = 32 + gl; i < deg; i += 16) {
        int s = sorted_src[r0 + i];
        float e = s_src[s] + sd;
        e = (e > 0.f) ? e : 0.2f * e;
        m = fmaxf(m, e);
    }
#pragma unroll
    for (int mk = 8; mk >= 1; mk >>= 1) m = fmaxf(m, __shfl_xor(m, mk));

    float pv0 = (gl < deg) ? __expf(ev0 - m) : 0.f;
    float pv1 = (16 + gl < deg) ? __expf(ev1 - m) : 0.f;
    float den = pv0 + pv1;
    for (int i = 32 + gl; i < deg; i += 16) {
        int s = sorted_src[r0 + i];
        float e = s_src[s] + sd;
        e = (e > 0.f) ? e : 0.2f * e;
        den += __expf(e - m);
    }
#pragma unroll
    for (int mk = 8; mk >= 1; mk >>= 1) den += __shfl_xor(den, mk);

    float acc[8];
#pragma unroll
    for (int k = 0; k < 8; ++k) acc[k] = 0.f;

    int jm = (deg < 32) ? deg : 32;
#pragma unroll 4
    for (int j = 0; j < jm; ++j) {
        int src_lane = gbase + (j & 15);
        int s = __shfl((j < 16) ? sv0 : sv1, src_lane);
        float p = __shfl((j < 16) ? pv0 : pv1, src_lane);
        bf16x8 hv = *(const bf16x8*)(h + (size_t)s * 128 + gl * 8);
#pragma unroll
        for (int k = 0; k < 8; ++k) acc[k] += p * (float)hv[k];
    }
    for (int i = 32; i < deg; ++i) {
        int s = sorted_src[r0 + i];
        float e = s_src[s] + sd;
        e = (e > 0.f) ? e : 0.2f * e;
        float p = __expf(e - m);
        bf16x8 hv = *(const bf16x8*)(h + (size_t)s * 128 + gl * 8);
#pragma unroll
        for (int k = 0; k < 8; ++k) acc[k] += p * (float)hv[k];
    }

    float inv = 1.f / den;
    float4 bv0 = *(const float4*)(bias + gl * 8);
    float4 bv1 = *(const float4*)(bias + gl * 8 + 4);
    float o[8] = {acc[0] * inv + bv0.x, acc[1] * inv + bv0.y,
                  acc[2] * inv + bv0.z, acc[3] * inv + bv0.w,
                  acc[4] * inv + bv1.x, acc[5] * inv + bv1.y,
                  acc[6] * inv + bv1.z, acc[7] * inv + bv1.w};
    if constexpr (sizeof(OUT_T) == 2) {
        bf16x8 ov;
#pragma unroll
        for (int k = 0; k < 8; ++k) ov[k] = (bf16)o[k];
        *(bf16x8*)((bf16*)out + (size_t)d * 128 + gl * 8) = ov;
    } else {
        float* op = (float*)out + (size_t)d * 128 + gl * 8;
        *(float4*)op       = (float4){o[0], o[1], o[2], o[3]};
        *(float4*)(op + 4) = (float4){o[4], o[5], o[6], o[7]};
    }
}

// ---------------- per-graph mean/max pooling (batch_idx sorted) ----------------
__global__ __launch_bounds__(256)
void pool_kernel(const float* __restrict__ out2, const int* __restrict__ batch_idx,
                 float* __restrict__ mean, float* __restrict__ mx) {
    int g = blockIdx.x;
    int j = threadIdx.x & 127;
    int grp = threadIdx.x >> 7;
    int lo = 0, hi = N_NODES;
    while (lo < hi) { int mid = (lo + hi) >> 1; if (batch_idx[mid] < g) lo = mid + 1; else hi = mid; }
    int start = lo;
    hi = N_NODES;
    while (lo < hi) { int mid = (lo + hi) >> 1; if (batch_idx[mid] < g + 1) lo = mid + 1; else hi = mid; }
    int end = lo;

    float s = 0.f, mmax = -INFINITY;
    for (int r = start + grp; r < end; r += 2) {
        float v = out2[(size_t)r * 128 + j];
        s += v;
        mmax = fmaxf(mmax, v);
    }
    __shared__ float ls[2][128], lm[2][128];
    ls[grp][j] = s; lm[grp][j] = mmax;
    __syncthreads();
    if (grp == 0) {
        int cnt = end - start;
        float sum = ls[0][j] + ls[1][j];
        float mv = fmaxf(lm[0][j], lm[1][j]);
        mean[g * 128 + j] = sum / fmaxf((float)cnt, 1.f);
        mx[g * 128 + j] = (cnt > 0) ? mv : 0.f;
    }
}

// ---------------- head ----------------
__global__ __launch_bounds__(128)
void head_kernel(const float* __restrict__ mean, const float* __restrict__ mx,
                 const float* __restrict__ gfeat, const float* __restrict__ Wg,
                 const float* __restrict__ bg, const float* __restrict__ Wo,
                 const float* __restrict__ bo, float* __restrict__ out) {
    int g = blockIdx.x;
    int j = threadIdx.x;
    float gft = bg[j];
#pragma unroll
    for (int k = 0; k < 32; ++k)
        gft += gfeat[g * 32 + k] * Wg[k * 128 + j];
    float mj = mean[g * 128 + j], xj = mx[g * 128 + j];
    float p0 = mj * Wo[j * 2 + 0] + xj * Wo[(128 + j) * 2 + 0] + gft * Wo[(256 + j) * 2 + 0];
    float p1 = mj * Wo[j * 2 + 1] + xj * Wo[(128 + j) * 2 + 1] + gft * Wo[(256 + j) * 2 + 1];
#pragma unroll
    for (int m = 32; m >= 1; m >>= 1) { p0 += __shfl_xor(p0, m); p1 += __shfl_xor(p1, m); }
    __shared__ float l0s[2], l1s[2];
    int wv = j >> 6;
    if ((j & 63) == 0) { l0s[wv] = p0; l1s[wv] = p1; }
    __syncthreads();
    if (j == 0) {
        float l0 = l0s[0] + l0s[1] + bo[0];
        float l1 = l1s[0] + l1s[1] + bo[1];
        float mm = fmaxf(l0, l1);
        float lse = mm + logf(__expf(l0 - mm) + __expf(l1 - mm));
        out[g * 2 + 0] = l0 - lse;
        out[g * 2 + 1] = l1 - lse;
    }
}

extern "C" void kernel_launch(void* const* d_in, const int* in_sizes, int n_in,
                              void* d_out, int out_size, void* d_ws, size_t ws_size,
                              hipStream_t stream) {
    const float* x     = (const float*)d_in[0];
    const int*   edges = (const int*)d_in[1];
    const int*   batch = (const int*)d_in[2];
    const float* gfeat = (const float*)d_in[3];
    const float* W1    = (const float*)d_in[4];
    const float* a1s   = (const float*)d_in[5];
    const float* a1d   = (const float*)d_in[6];
    const float* b1    = (const float*)d_in[7];
    const float* W2    = (const float*)d_in[8];
    const float* a2s   = (const float*)d_in[9];
    const float* a2d   = (const float*)d_in[10];
    const float* b2    = (const float*)d_in[11];
    const float* Wg    = (const float*)d_in[12];
    const float* bg    = (const float*)d_in[13];
    const float* Wo    = (const float*)d_in[14];
    const float* bo    = (const float*)d_in[15];

    char* ws = (char*)d_ws;
    bf16*  WT1        = (bf16*)(ws + 0);          //  65536 B
    bf16*  WT2        = (bf16*)(ws + 65536);      //  32768 B
    float* s_src      = (float*)(ws + 98304);     // 200704 B
    float* s_dst      = (float*)(ws + 299008);    // 200704 B
    int*   subcur     = (int*)(ws + 499712);      // NSLOT*4 = 12512 B
    int*   bucketbase = (int*)(ws + 513792);      // 1568 B
    int*   offsets    = (int*)(ws + 520192);      // 200704 B (N+1 ints)
    int*   sorted     = (int*)(ws + 720896);      // 3400704 B
    bf16*  h          = (bf16*)(ws + 4502528);    // 12.8 MB
    bf16*  out1       = (bf16*)(ws + 17302528);   // 12.8 MB
    float* out2       = (float*)(ws + 30102528);  // 25.6 MB
    int2*  pairs      = (int2*)(ws + 30102528);   // 11.2 MB, ALIASES out2 (dead by then)
    float* pmean      = (float*)(ws + 55702528);  // 131072 B
    float* pmax       = (float*)(ws + 55833600);  // 131072 B

    const int* e_src = edges;
    const int* e_dst = edges + N_EDGES;

    // --- W transposes + f32->bf16 cast (tiny) ---
    transpose_kernel<<<(FIN * EMB + 255) / 256, 256, 0, stream>>>(W1, WT1, FIN, EMB);
    transpose_kernel<<<(EMB * EMB + 255) / 256, 256, 0, stream>>>(W2, WT2, EMB, EMB);

    // --- CSR by dst: two-phase bucket sort ---
    hipMemsetAsync(subcur, 0, NSLOT * sizeof(int), stream);
    int qb = (N_EDGES / 4 + 255) / 256;   // 782
    bucket_scatter_kernel<<<qb, 256, 0, stream>>>(e_src, e_dst, subcur, pairs);
    bucket_scan_kernel<<<1, 1024, 0, stream>>>(subcur, bucketbase, offsets);
    bucket_build_kernel<<<NB, 1024, 0, stream>>>(subcur, bucketbase, pairs, offsets, sorted);

    int gemm_blocks = (N_NODES + 63) / 64;
    int agg_blocks = (N_NODES + 15) / 16;

    // --- layer 1 (scores fused into gemm epilogue) ---
    gemm_kernel<FIN, float><<<gemm_blocks, 256, 0, stream>>>(x, WT1, h, N_NODES,
                                                             a1s, a1d, s_src, s_dst);
    agg_kernel<bf16><<<agg_blocks, 256, 0, stream>>>(offsets, sorted, s_src, s_dst, h, b1, out1);

    // --- layer 2 ---
    gemm_kernel<EMB, bf16><<<gemm_blocks, 256, 0, stream>>>(out1, WT2, h, N_NODES,
                                                            a2s, a2d, s_src, s_dst);
    agg_kernel<float><<<agg_blocks, 256, 0, stream>>>(offsets, sorted, s_src, s_dst, h, b2, out2);

    // --- pooling + head ---
    pool_kernel<<<NGRAPH, 256, 0, stream>>>(out2, batch, pmean, pmax);
    head_kernel<<<NGRAPH, 128, 0, stream>>>(pmean, pmax, gfeat, Wg, bg, Wo, bo, (float*)d_out);
}